// Round 2
// baseline (394.214 us; speedup 1.0000x reference)
//
#include <hip/hip_runtime.h>

#define SEQn   512
#define BATCHn 4096
#define INn    9
#define HIDn   64
#define OUTn   10

typedef __attribute__((ext_vector_type(4))) float    f32x4;
typedef __attribute__((ext_vector_type(4))) _Float16 f16x4;
typedef unsigned short u16;
typedef unsigned int   u32;

// D = A(16x16,f16) * B(16x16,f16) + C(f32)
#define MFMA16(A,B,C) __builtin_amdgcn_mfma_f32_16x16x16f16((A),(B),(C),0,0,0)

// tanh(y) given x = 2*log2(e)*y  (the 2*log2e factor is pre-folded into the weights)
__device__ __forceinline__ float tanh_pre(float x){
    float e = __builtin_amdgcn_exp2f(x);
    float r = __builtin_amdgcn_rcpf(e + 1.0f);
    return __builtin_fmaf(-2.0f, r, 1.0f);
}
__device__ __forceinline__ u16 f2h(float v){ return __builtin_bit_cast(u16, (_Float16)v); }
__device__ __forceinline__ f16x4 cvt4(f32x4 a){
    f16x4 r = {(_Float16)a.x, (_Float16)a.y, (_Float16)a.z, (_Float16)a.w};
    return r;
}

// Register-resident MFMA recurrence. Key identity for v_mfma_f32_16x16x16_f16:
//   A frag: lane l holds A[m=l&15][k=4*(l>>4)+i]
//   B frag: lane l holds B[k=4*(l>>4)+i][n=l&15]
//   D frag: lane l holds D[m=4*(l>>4)+i][n=l&15]
// With the state vector replicated across all 16 B-columns, the D fragment of
// row-block r IS the B fragment of k-block r for the next step -> the h1/h2
// recurrences never touch LDS. u2 = K*(Wih1*h1+b2) flows wave0->wave1 via the
// f32 ring + watermark protocol. Spin loops are BOUNDED: a protocol bug
// degrades to a wrong answer instead of a hang (protects the harness).
extern "C" __global__ __launch_bounds__(256, 1)
void rnn_lastrow(const float* __restrict__ x,
                 const float* __restrict__ Wih0, const float* __restrict__ Whh0,
                 const float* __restrict__ bih0, const float* __restrict__ bhh0,
                 const float* __restrict__ Wih1, const float* __restrict__ Whh1,
                 const float* __restrict__ bih1, const float* __restrict__ bhh1,
                 const float* __restrict__ Wfc,  const float* __restrict__ bfc,
                 float* __restrict__ out)
{
    __shared__ __align__(16) u16   xl16[SEQn*16];   // x[:,4095,:] as f16, rows padded to 16
    __shared__ __align__(16) float u2r[64*HIDn];    // u2 ring, 64 slots, f32
    __shared__ u32 wm[2];                           // [0]=u2 slots ready, [1]=consumer iter

    const int tid  = threadIdx.x;
    const int w    = tid >> 6;
    const int lane = tid & 63;
    const int g    = lane >> 4;    // fragment k/row group
    const int n    = lane & 15;    // fragment column
    volatile u32* vwm = wm;
    const float K = 2.8853900817779268f;   // 2*log2(e)

    // ---- stage x[:,4095,:] as f16 (all 4 waves) ----
    for (int idx = tid; idx < SEQn*16; idx += 256){
        int t = idx >> 4, j = idx & 15;
        float v = (j < INn) ? x[((long)t*BATCHn + (BATCHn-1))*INn + j] : 0.f;
        xl16[idx] = f2h(v);
    }
    if (tid == 0){ wm[0] = 0u; wm[1] = 0u; }
    __syncthreads();
    if (w >= 2) return;

    if (w == 0){
        // ================= wave0: h1 chain + u2 =================
        f16x4 wh0[4][4], wi1[4][4], wx[4];
        f32x4 b1f[4], b2f[4];
#pragma unroll
        for (int r = 0; r < 4; ++r){
            f32x4 bi  = *(const f32x4*)&bih0[16*r + 4*g];
            f32x4 bh  = *(const f32x4*)&bhh0[16*r + 4*g];
            b1f[r] = (bi + bh) * K;
            f32x4 bi1 = *(const f32x4*)&bih1[16*r + 4*g];
            f32x4 bh1 = *(const f32x4*)&bhh1[16*r + 4*g];
            b2f[r] = (bi1 + bh1) * K;
#pragma unroll
            for (int c = 0; c < 4; ++c){
                f32x4 a0 = *(const f32x4*)&Whh0[(16*r + n)*HIDn + 16*c + 4*g];
                wh0[r][c] = cvt4(a0 * K);
                f32x4 a1 = *(const f32x4*)&Wih1[(16*r + n)*HIDn + 16*c + 4*g];
                wi1[r][c] = cvt4(a1 * K);
            }
            // Wih0 block (K dim = 9, zero-padded to 16)
            int base = (16*r + n)*INn, k0 = 4*g;
            f16x4 e;
            e.x = (_Float16)((k0+0 < INn) ? Wih0[base + k0+0]*K : 0.f);
            e.y = (_Float16)((k0+1 < INn) ? Wih0[base + k0+1]*K : 0.f);
            e.z = (_Float16)((k0+2 < INn) ? Wih0[base + k0+2]*K : 0.f);
            e.w = (_Float16)((k0+3 < INn) ? Wih0[base + k0+3]*K : 0.f);
            wx[r] = e;
        }
        f16x4 hz = {(_Float16)0.f, (_Float16)0.f, (_Float16)0.f, (_Float16)0.f};
        f16x4 hb[4] = {hz, hz, hz, hz};

        auto w0step = [&](int p, f16x4& XC, f16x4& XN){
            if ((p & 7) == 0){
                asm volatile("s_waitcnt lgkmcnt(0)" ::: "memory");
                vwm[0] = (u32)(p ? p-1 : 0);
                int guard = 1 << 20;
                while ((vwm[1] + 56u <= (u32)p) && --guard) __builtin_amdgcn_s_sleep(2);
                asm volatile("" ::: "memory");
            }
            XN = *(const f16x4*)&xl16[((p+1) & (SEQn-1))*16 + 4*g];   // prefetch next x frag
            f32x4 acc[4], u2a[4];
#pragma unroll
            for (int r = 0; r < 4; ++r){
                acc[r] = MFMA16(wx[r], XC, b1f[r]);   // K*(Wih0 x + b1)
                u2a[r] = b2f[r];
            }
#pragma unroll
            for (int c = 0; c < 4; ++c)
#pragma unroll
                for (int r = 0; r < 4; ++r){
                    acc[r] = MFMA16(wh0[r][c], hb[c], acc[r]);   // + K*Whh0 h1[p-1]
                    u2a[r] = MFMA16(wi1[r][c], hb[c], u2a[r]);   // u2[p-1] in shadow
                }
            if (p && ((lane & 15) == 0)){          // publish u2[p-1] (cols replicated)
                int s = (p-1) & 63;
#pragma unroll
                for (int r = 0; r < 4; ++r)
                    *(f32x4*)&u2r[s*HIDn + 16*r + 4*g] = u2a[r];
            }
#pragma unroll
            for (int r = 0; r < 4; ++r){           // h1[p] = tanh, D frag == next B frag
                f32x4 t;
                t.x = tanh_pre(acc[r].x); t.y = tanh_pre(acc[r].y);
                t.z = tanh_pre(acc[r].z); t.w = tanh_pre(acc[r].w);
                hb[r] = cvt4(t);
            }
        };

        f16x4 xfA = *(const f16x4*)&xl16[0*16 + 4*g];
        f16x4 xfB;
        for (int p = 0; p < SEQn; p += 2){
            w0step(p,     xfA, xfB);
            w0step(p + 1, xfB, xfA);
        }
        {   // epilogue: u2[511] from final hb
            f32x4 u2a[4];
#pragma unroll
            for (int r = 0; r < 4; ++r) u2a[r] = b2f[r];
#pragma unroll
            for (int c = 0; c < 4; ++c)
#pragma unroll
                for (int r = 0; r < 4; ++r)
                    u2a[r] = MFMA16(wi1[r][c], hb[c], u2a[r]);
            if ((lane & 15) == 0){
                int s = (SEQn-1) & 63;
#pragma unroll
                for (int r = 0; r < 4; ++r)
                    *(f32x4*)&u2r[s*HIDn + 16*r + 4*g] = u2a[r];
            }
            asm volatile("s_waitcnt lgkmcnt(0)" ::: "memory");
            vwm[0] = 4096u;
        }
    } else {
        // ================= wave1: h2 chain + FC =================
        f16x4 wh1[4][4], wfc4[4];
        f32x4 bfcf;
#pragma unroll
        for (int r = 0; r < 4; ++r)
#pragma unroll
            for (int c = 0; c < 4; ++c){
                f32x4 a = *(const f32x4*)&Whh1[(16*r + n)*HIDn + 16*c + 4*g];
                wh1[r][c] = cvt4(a * K);
            }
        {
            int mrow = (n < OUTn) ? n : (OUTn-1);   // clamp pad rows (outputs unused)
#pragma unroll
            for (int c = 0; c < 4; ++c)
                wfc4[c] = cvt4(*(const f32x4*)&Wfc[mrow*HIDn + 16*c + 4*g]);  // no K
            int o0 = 4*g;
            bfcf.x = (o0+0 < OUTn) ? bfc[o0+0] : 0.f;
            bfcf.y = (o0+1 < OUTn) ? bfc[o0+1] : 0.f;
            bfcf.z = (o0+2 < OUTn) ? bfc[o0+2] : 0.f;
            bfcf.w = (o0+3 < OUTn) ? bfc[o0+3] : 0.f;
        }
        f16x4 hz = {(_Float16)0.f, (_Float16)0.f, (_Float16)0.f, (_Float16)0.f};
        f16x4 hb2[4] = {hz, hz, hz, hz};

        auto store_fc = [&](int t, f32x4 v){
            if (((lane & 15) == 0) && g < 3){   // D rows o=4g+i, cols replicated
                float* o = out + t*OUTn + 4*g;
                o[0] = v.x; o[1] = v.y;
                if (g < 2){ o[2] = v.z; o[3] = v.w; }
            }
        };
        auto w1step = [&](int c, f32x4* CU, f32x4* NX){
            if ((c & 7) == 0){
                vwm[1] = (u32)c;
                int guard = 1 << 20;
                while ((vwm[0] < (u32)(c + 9)) && --guard) __builtin_amdgcn_s_sleep(2);
                asm volatile("" ::: "memory");
                if (c == 0){
#pragma unroll
                    for (int r = 0; r < 4; ++r)
                        CU[r] = *(const f32x4*)&u2r[16*r + 4*g];
                }
            }
#pragma unroll
            for (int r = 0; r < 4; ++r)   // prefetch u2[c+1] frags
                NX[r] = *(const f32x4*)&u2r[((c+1) & 63)*HIDn + 16*r + 4*g];
            if (c){                        // FC[c-1] in shadow, from hb2 = h2[c-1]
                f32x4 fca = bfcf;
#pragma unroll
                for (int cc = 0; cc < 4; ++cc)
                    fca = MFMA16(wfc4[cc], hb2[cc], fca);
                store_fc(c-1, fca);
            }
            f32x4 acc[4];
#pragma unroll
            for (int r = 0; r < 4; ++r) acc[r] = CU[r];      // K*(Wih1 h1[c] + b2)
#pragma unroll
            for (int cc = 0; cc < 4; ++cc)
#pragma unroll
                for (int r = 0; r < 4; ++r)
                    acc[r] = MFMA16(wh1[r][cc], hb2[cc], acc[r]);
#pragma unroll
            for (int r = 0; r < 4; ++r){
                f32x4 t;
                t.x = tanh_pre(acc[r].x); t.y = tanh_pre(acc[r].y);
                t.z = tanh_pre(acc[r].z); t.w = tanh_pre(acc[r].w);
                hb2[r] = cvt4(t);
            }
        };

        f32x4 uA[4], uB[4];
        for (int c = 0; c < SEQn; c += 2){
            w1step(c,     uA, uB);
            w1step(c + 1, uB, uA);
        }
        {   // epilogue: FC[511]
            f32x4 fca = bfcf;
#pragma unroll
            for (int cc = 0; cc < 4; ++cc)
                fca = MFMA16(wfc4[cc], hb2[cc], fca);
            store_fc(SEQn-1, fca);
        }
    }
}

extern "C" void kernel_launch(void* const* d_in, const int* in_sizes, int n_in,
                              void* d_out, int out_size, void* d_ws, size_t ws_size,
                              hipStream_t stream){
    rnn_lastrow<<<dim3(1), dim3(256), 0, stream>>>(
        (const float*)d_in[0],
        (const float*)d_in[1], (const float*)d_in[2],
        (const float*)d_in[3], (const float*)d_in[4],
        (const float*)d_in[5], (const float*)d_in[6],
        (const float*)d_in[7], (const float*)d_in[8],
        (const float*)d_in[9], (const float*)d_in[10],
        (float*)d_out);
}

// Round 3
// 241.145 us; speedup vs baseline: 1.6348x; 1.6348x over previous
//
#include <hip/hip_runtime.h>

#define SEQn   512
#define BATCHn 4096
#define INn    9
#define HIDn   64
#define OUTn   10
#define ROW1   72          // u16 elems per h-ring row (144 B, 16B-aligned, pad kills bank conflicts)
#define U2P    72          // f32 elems per u2 ring row (288 B)

typedef __attribute__((ext_vector_type(4))) float    f32x4;
typedef __attribute__((ext_vector_type(4))) _Float16 f16x4;
typedef _Float16 half2_t __attribute__((ext_vector_type(2)));
typedef unsigned short u16;
typedef unsigned int   u32;

#define MFMA16(A,B,C) __builtin_amdgcn_mfma_f32_16x16x16f16((A),(B),(C),0,0,0)

#if __has_builtin(__builtin_amdgcn_fdot2)
#define DOT2(a,b,c) __builtin_amdgcn_fdot2((a),(b),(c),false)
#else
__device__ __forceinline__ float DOT2(half2_t a, half2_t b, float c){
    return __builtin_fmaf((float)a.x,(float)b.x, __builtin_fmaf((float)a.y,(float)b.y,c));
}
#endif
#define H2(u) __builtin_bit_cast(half2_t, (u))

// tanh(y) given x = 2*log2(e)*y  (2*log2e pre-folded into weights/biases)
__device__ __forceinline__ float tanh_pre(float x){
    float e = __builtin_amdgcn_exp2f(x);
    float r = __builtin_amdgcn_rcpf(e + 1.0f);
    return __builtin_fmaf(-2.0f, r, 1.0f);
}
__device__ __forceinline__ u16 f2h(float v){ return __builtin_bit_cast(u16, (_Float16)v); }
__device__ __forceinline__ f16x4 cvt4(f32x4 a){
    f16x4 r = {(_Float16)a.x, (_Float16)a.y, (_Float16)a.z, (_Float16)a.w};
    return r;
}

// lane-owned weight row scaled by s: 64 f32 -> 32 half2 regs (for DOT2 matvec)
__device__ __forceinline__ void load_w16s(const float* __restrict__ W, int row, float s, half2_t* wr){
#pragma unroll
    for (int c = 0; c < 16; ++c){
        f32x4 v = *(const f32x4*)&W[row*HIDn + c*4];
        wr[2*c]   = half2_t{(_Float16)(v.x*s), (_Float16)(v.y*s)};
        wr[2*c+1] = half2_t{(_Float16)(v.z*s), (_Float16)(v.w*s)};
    }
}

// 64-dot: v = 8 x uint4 (64 f16), wr = 32 half2 regs, fp32 accumulate
__device__ __forceinline__ float dot64r(const uint4* v, const half2_t* wr, float acc){
    float a0 = acc, a1 = 0.f, a2 = 0.f, a3 = 0.f;
#pragma unroll
    for (int jb = 0; jb < 8; ++jb){
        a0 = DOT2(H2(v[jb].x), wr[jb*4+0], a0);
        a1 = DOT2(H2(v[jb].y), wr[jb*4+1], a1);
        a2 = DOT2(H2(v[jb].z), wr[jb*4+2], a2);
        a3 = DOT2(H2(v[jb].w), wr[jb*4+3], a3);
    }
    return (a0 + a1) + (a2 + a3);
}

// DOT2 recurrences (1 tanh/lane) + MFMA-batched shadows (u2 / FC computed for
// 16 timesteps at once from a 16-slot h-history ring; n-dim of the MFMA = time).
// wave0: h1 chain, every 16 steps 16 MFMAs produce u2[p-16..p-1] -> 64-slot ring.
// wave1: h2 chain, every 16 steps 4 MFMAs produce FC[c-16..c-1] -> global out.
extern "C" __global__ __launch_bounds__(256, 1)
void rnn_lastrow(const float* __restrict__ x,
                 const float* __restrict__ Wih0, const float* __restrict__ Whh0,
                 const float* __restrict__ bih0, const float* __restrict__ bhh0,
                 const float* __restrict__ Wih1, const float* __restrict__ Whh1,
                 const float* __restrict__ bih1, const float* __restrict__ bhh1,
                 const float* __restrict__ Wfc,  const float* __restrict__ bfc,
                 float* __restrict__ out)
{
    __shared__ __align__(16) u16   xl16[SEQn*16];    // x[:,4095,:] f16, rows padded to 16
    __shared__ __align__(16) float u2r[64*U2P];      // u2 ring, 64 slots
    __shared__ __align__(16) u16   ring1[16*ROW1];   // h1 history (f16)
    __shared__ __align__(16) u16   ring2[16*ROW1];   // h2 history (f16)
    __shared__ u32 wm[2];                            // [0]=u2 ready count, [1]=consumer iter

    const int tid  = threadIdx.x;
    const int w    = tid >> 6;
    const int lane = tid & 63;
    const int g    = lane >> 4;
    const int n    = lane & 15;
    volatile u32* vwm = wm;
    const float K = 2.8853900817779268f;   // 2*log2(e)

    for (int idx = tid; idx < SEQn*16; idx += 256){
        int t = idx >> 4, j = idx & 15;
        float v = (j < INn) ? x[((long)t*BATCHn + (BATCHn-1))*INn + j] : 0.f;
        xl16[idx] = f2h(v);
    }
    for (int idx = tid; idx < 16*ROW1; idx += 256){ ring1[idx] = 0; ring2[idx] = 0; }
    if (tid == 0){ wm[0] = 0u; wm[1] = 0u; }
    __syncthreads();
    if (w >= 2) return;

    if (w == 0){
        // ================= wave0: h1 chain (DOT2) + u2 batches (MFMA) =================
        half2_t wr0[32], wx[5];
        load_w16s(Whh0, lane, K, wr0);
        {
            const float* wxr = Wih0 + lane*INn;
#pragma unroll
            for (int q = 0; q < 4; ++q)
                wx[q] = half2_t{(_Float16)(wxr[2*q]*K), (_Float16)(wxr[2*q+1]*K)};
            wx[4] = half2_t{(_Float16)(wxr[8]*K), (_Float16)0.f};
        }
        const float b1 = (bih0[lane] + bhh0[lane]) * K;

        f16x4 wi1[4][4]; f32x4 b2f[4];
#pragma unroll
        for (int r = 0; r < 4; ++r){
            f32x4 bi1 = *(const f32x4*)&bih1[16*r + 4*g];
            f32x4 bh1 = *(const f32x4*)&bhh1[16*r + 4*g];
            b2f[r] = (bi1 + bh1) * K;
#pragma unroll
            for (int c = 0; c < 4; ++c){
                f32x4 a1 = *(const f32x4*)&Wih1[(16*r + n)*HIDn + 16*c + 4*g];
                wi1[r][c] = cvt4(a1 * K);   // A-frag: lane holds A[m=n][k=16c+4g+i]
            }
        }

        // u2[t] for t in [p0-16, p0): B[k][nn] = h1[p0-16+nn][k], ring slot nn = n
        auto u2batch = [&](int p0){
            f16x4 B[4];
#pragma unroll
            for (int c = 0; c < 4; ++c)
                B[c] = *(const f16x4*)&ring1[n*ROW1 + 16*c + 4*g];
            f32x4 D[4];
#pragma unroll
            for (int r = 0; r < 4; ++r) D[r] = b2f[r];
#pragma unroll
            for (int c = 0; c < 4; ++c)
#pragma unroll
                for (int r = 0; r < 4; ++r)
                    D[r] = MFMA16(wi1[r][c], B[c], D[r]);
            int t = (p0 - 16 + n) & 63;    // D[m][nn]: lane holds rows 16r+4g+i, col nn=n
#pragma unroll
            for (int r = 0; r < 4; ++r)
                *(f32x4*)&u2r[t*U2P + 16*r + 4*g] = D[r];
        };

        for (int p = 0; p < SEQn; ++p){
            if ((p & 15) == 0 && p){
                int guard = 1 << 20;       // ring-space: need consumer past p-63
                while ((vwm[1] + 64u <= (u32)p) && --guard) __builtin_amdgcn_s_sleep(2);
                asm volatile("" ::: "memory");
                u2batch(p);
                asm volatile("s_waitcnt lgkmcnt(0)" ::: "memory");
                vwm[0] = (u32)p;
            }
            const u32* xr = (const u32*)(xl16 + p*16);
            uint4 xa = *(const uint4*)xr;
            u32  xb  = xr[4];
            uint4 CUR[8];
            const uint4* hrow = (const uint4*)(ring1 + ((p-1) & 15)*ROW1);
#pragma unroll
            for (int j = 0; j < 8; ++j) CUR[j] = hrow[j];
            float u1 = b1;
            u1 = DOT2(H2(xa.x), wx[0], u1);
            u1 = DOT2(H2(xa.y), wx[1], u1);
            u1 = DOT2(H2(xa.z), wx[2], u1);
            u1 = DOT2(H2(xa.w), wx[3], u1);
            u1 = DOT2(H2(xb),   wx[4], u1);
            float y = dot64r(CUR, wr0, u1);
            ring1[(p & 15)*ROW1 + lane] = f2h(tanh_pre(y));
        }
        {   // epilogue: u2[496..511]
            int guard = 1 << 20;
            while ((vwm[1] + 64u <= (u32)SEQn) && --guard) __builtin_amdgcn_s_sleep(2);
            asm volatile("" ::: "memory");
            u2batch(SEQn);
            asm volatile("s_waitcnt lgkmcnt(0)" ::: "memory");
            vwm[0] = (u32)SEQn;
        }
    } else {
        // ================= wave1: h2 chain (DOT2) + FC batches (MFMA) =================
        half2_t wr2[32];
        load_w16s(Whh1, lane, K, wr2);
        f16x4 wfcA[4]; f32x4 bfcf;
        {
            int mrow = (n < OUTn) ? n : (OUTn - 1);   // clamp pad rows (never stored)
#pragma unroll
            for (int c = 0; c < 4; ++c)
                wfcA[c] = cvt4(*(const f32x4*)&Wfc[mrow*HIDn + 16*c + 4*g]);  // unscaled
            int o0 = 4*g;
            bfcf.x = (o0+0 < OUTn) ? bfc[o0+0] : 0.f;
            bfcf.y = (o0+1 < OUTn) ? bfc[o0+1] : 0.f;
            bfcf.z = (o0+2 < OUTn) ? bfc[o0+2] : 0.f;
            bfcf.w = (o0+3 < OUTn) ? bfc[o0+3] : 0.f;
        }

        auto fcbatch = [&](int c0){        // FC[t] for t in [c0-16, c0)
            f16x4 B[4];
#pragma unroll
            for (int c = 0; c < 4; ++c)
                B[c] = *(const f16x4*)&ring2[n*ROW1 + 16*c + 4*g];
            f32x4 D = bfcf;
#pragma unroll
            for (int c = 0; c < 4; ++c)
                D = MFMA16(wfcA[c], B[c], D);
            int t = c0 - 16 + n;
            float* o = out + t*OUTn + 4*g;
            if (g < 2){ o[0] = D.x; o[1] = D.y; o[2] = D.z; o[3] = D.w; }
            else if (g == 2){ o[0] = D.x; o[1] = D.y; }
        };

        for (int c = 0; c < SEQn; ++c){
            if ((c & 15) == 0){
                vwm[1] = (u32)c;
                if (c) fcbatch(c);         // independent of producer: overlaps the wait
                int guard = 1 << 20;
                while ((vwm[0] < (u32)(c + 16)) && --guard) __builtin_amdgcn_s_sleep(1);
                asm volatile("" ::: "memory");
            }
            float u2v = u2r[(c & 63)*U2P + lane];
            uint4 CUR[8];
            const uint4* hrow = (const uint4*)(ring2 + ((c-1) & 15)*ROW1);
#pragma unroll
            for (int j = 0; j < 8; ++j) CUR[j] = hrow[j];
            float y = dot64r(CUR, wr2, u2v);
            ring2[(c & 15)*ROW1 + lane] = f2h(tanh_pre(y));
        }
        fcbatch(SEQn);                     // FC[496..511]
    }
}

extern "C" void kernel_launch(void* const* d_in, const int* in_sizes, int n_in,
                              void* d_out, int out_size, void* d_ws, size_t ws_size,
                              hipStream_t stream){
    rnn_lastrow<<<dim3(1), dim3(256), 0, stream>>>(
        (const float*)d_in[0],
        (const float*)d_in[1], (const float*)d_in[2],
        (const float*)d_in[3], (const float*)d_in[4],
        (const float*)d_in[5], (const float*)d_in[6],
        (const float*)d_in[7], (const float*)d_in[8],
        (const float*)d_in[9], (const float*)d_in[10],
        (float*)d_out);
}

// Round 4
// 238.148 us; speedup vs baseline: 1.6553x; 1.0126x over previous
//
#include <hip/hip_runtime.h>

#define SEQn   512
#define BATCHn 4096
#define INn    9
#define HIDn   64
#define OUTn   10
#define ROW1   72          // u16 elems per h-ring row (144 B: pad kills power-of-2 conflicts)
#define U2P    72          // f32 elems per u2 ring row (288 B)

typedef __attribute__((ext_vector_type(4))) float    f32x4;
typedef __attribute__((ext_vector_type(4))) _Float16 f16x4;
typedef _Float16 half2_t __attribute__((ext_vector_type(2)));
typedef unsigned short u16;
typedef unsigned int   u32;

#define MFMA16(A,B,C) __builtin_amdgcn_mfma_f32_16x16x16f16((A),(B),(C),0,0,0)

#if __has_builtin(__builtin_amdgcn_fdot2)
#define DOT2(a,b,c) __builtin_amdgcn_fdot2((a),(b),(c),false)
#else
__device__ __forceinline__ float DOT2(half2_t a, half2_t b, float c){
    return __builtin_fmaf((float)a.x,(float)b.x, __builtin_fmaf((float)a.y,(float)b.y,c));
}
#endif
#define H2(u) __builtin_bit_cast(half2_t, (u))

// tanh(y) given x = 2*log2(e)*y  (2*log2e pre-folded into weights/biases)
__device__ __forceinline__ float tanh_pre(float x){
    float e = __builtin_amdgcn_exp2f(x);
    float r = __builtin_amdgcn_rcpf(e + 1.0f);
    return __builtin_fmaf(-2.0f, r, 1.0f);
}
__device__ __forceinline__ u16 f2h(float v){ return __builtin_bit_cast(u16, (_Float16)v); }
__device__ __forceinline__ f16x4 cvt4(f32x4 a){
    f16x4 r = {(_Float16)a.x, (_Float16)a.y, (_Float16)a.z, (_Float16)a.w};
    return r;
}

// lane-owned weight row scaled by s: 64 f32 -> 32 half2 regs (for DOT2 matvec)
__device__ __forceinline__ void load_w16s(const float* __restrict__ W, int row, float s, half2_t* wr){
#pragma unroll
    for (int c = 0; c < 16; ++c){
        f32x4 v = *(const f32x4*)&W[row*HIDn + c*4];
        wr[2*c]   = half2_t{(_Float16)(v.x*s), (_Float16)(v.y*s)};
        wr[2*c+1] = half2_t{(_Float16)(v.z*s), (_Float16)(v.w*s)};
    }
}

// 64-dot, 8 accumulators x 4-deep chains (half the dep-latency of 4x8)
__device__ __forceinline__ float dot64r8(const uint4* v, const half2_t* wr, float acc){
    float s0=acc, s1=0.f, s2=0.f, s3=0.f, s4=0.f, s5=0.f, s6=0.f, s7=0.f;
#pragma unroll
    for (int q = 0; q < 4; ++q){
        s0 = DOT2(H2(v[2*q].x),   wr[8*q+0], s0);
        s1 = DOT2(H2(v[2*q].y),   wr[8*q+1], s1);
        s2 = DOT2(H2(v[2*q].z),   wr[8*q+2], s2);
        s3 = DOT2(H2(v[2*q].w),   wr[8*q+3], s3);
        s4 = DOT2(H2(v[2*q+1].x), wr[8*q+4], s4);
        s5 = DOT2(H2(v[2*q+1].y), wr[8*q+5], s5);
        s6 = DOT2(H2(v[2*q+1].z), wr[8*q+6], s6);
        s7 = DOT2(H2(v[2*q+1].w), wr[8*q+7], s7);
    }
    return ((s0+s1)+(s2+s3)) + ((s4+s5)+(s6+s7));
}

// 4-wave pipeline, watermark chain wm[0](h1)->wm[1](u2)->wm[2](h2)->wm[3](fc):
//   wave0: pure h1 DOT2 chain -> ring1 (64 slots)
//   wave2: u2 = K*(Wih1 h1 + b2) MFMA batches of 16 -> u2r (64 slots)
//   wave1: pure h2 DOT2 chain (reads u2r) -> ring2 (64 slots)
//   wave3: FC MFMA batches of 16 -> out
// Backpressure margins (48/64) proven: slot-reuse distance 64 > max
// producer-lookahead(16)+consumer-lag(47). All spins bounded (no-hang).
extern "C" __global__ __launch_bounds__(256, 1)
void rnn_lastrow(const float* __restrict__ x,
                 const float* __restrict__ Wih0, const float* __restrict__ Whh0,
                 const float* __restrict__ bih0, const float* __restrict__ bhh0,
                 const float* __restrict__ Wih1, const float* __restrict__ Whh1,
                 const float* __restrict__ bih1, const float* __restrict__ bhh1,
                 const float* __restrict__ Wfc,  const float* __restrict__ bfc,
                 float* __restrict__ out)
{
    __shared__ __align__(16) u16   xl16[SEQn*16];    // x[:,4095,:] f16, rows padded to 16
    __shared__ __align__(16) float u2r[64*U2P];      // u2 ring, 64 slots
    __shared__ __align__(16) u16   ring1[64*ROW1];   // h1 history (f16), 64 slots
    __shared__ __align__(16) u16   ring2[64*ROW1];   // h2 history (f16), 64 slots
    __shared__ u32 wm[4];

    const int tid  = threadIdx.x;
    const int w    = tid >> 6;
    const int lane = tid & 63;
    const int g    = lane >> 4;
    const int n    = lane & 15;
    volatile u32* vwm = wm;
    const float K = 2.8853900817779268f;   // 2*log2(e)

    for (int idx = tid; idx < SEQn*16; idx += 256){
        int t = idx >> 4, j = idx & 15;
        float v = (j < INn) ? x[((long)t*BATCHn + (BATCHn-1))*INn + j] : 0.f;
        xl16[idx] = f2h(v);
    }
    for (int idx = tid; idx < 64*ROW1; idx += 256){ ring1[idx] = 0; ring2[idx] = 0; }
    if (tid < 4) wm[tid] = 0u;
    __syncthreads();

    if (w == 0){
        // ---------------- wave0: h1 chain ----------------
        half2_t wr0[32], wx[5];
        load_w16s(Whh0, lane, K, wr0);
        {
            const float* wxr = Wih0 + lane*INn;
#pragma unroll
            for (int q = 0; q < 4; ++q)
                wx[q] = half2_t{(_Float16)(wxr[2*q]*K), (_Float16)(wxr[2*q+1]*K)};
            wx[4] = half2_t{(_Float16)(wxr[8]*K), (_Float16)0.f};
        }
        const float b1 = (bih0[lane] + bhh0[lane]) * K;

        for (int p = 0; p < SEQn; ++p){
            if ((p & 15) == 0 && p){
                asm volatile("s_waitcnt lgkmcnt(0)" ::: "memory");
                vwm[0] = (u32)p;
                int guard = 1 << 20;   // ring1 space: need u2 progress wm[1] >= p-48
                while ((vwm[1] + 48u < (u32)p) && --guard) __builtin_amdgcn_s_sleep(2);
                asm volatile("" ::: "memory");
            }
            const u32* xr = (const u32*)(xl16 + p*16);
            uint4 xa = *(const uint4*)xr;
            u32  xb  = xr[4];
            uint4 CUR[8];
            const uint4* hrow = (const uint4*)(ring1 + ((p-1) & 63)*ROW1);
#pragma unroll
            for (int j = 0; j < 8; ++j) CUR[j] = hrow[j];
            float u1 = b1;
            u1 = DOT2(H2(xa.x), wx[0], u1);
            u1 = DOT2(H2(xa.y), wx[1], u1);
            u1 = DOT2(H2(xa.z), wx[2], u1);
            u1 = DOT2(H2(xa.w), wx[3], u1);
            u1 = DOT2(H2(xb),   wx[4], u1);
            float y = dot64r8(CUR, wr0, u1);
            ring1[(p & 63)*ROW1 + lane] = f2h(tanh_pre(y));
        }
        asm volatile("s_waitcnt lgkmcnt(0)" ::: "memory");
        vwm[0] = (u32)SEQn;
    } else if (w == 2){
        // ---------------- wave2: u2 batches (MFMA) ----------------
        f16x4 wi1[4][4]; f32x4 b2f[4];
#pragma unroll
        for (int r = 0; r < 4; ++r){
            f32x4 bi1 = *(const f32x4*)&bih1[16*r + 4*g];
            f32x4 bh1 = *(const f32x4*)&bhh1[16*r + 4*g];
            b2f[r] = (bi1 + bh1) * K;
#pragma unroll
            for (int c = 0; c < 4; ++c){
                f32x4 a1 = *(const f32x4*)&Wih1[(16*r + n)*HIDn + 16*c + 4*g];
                wi1[r][c] = cvt4(a1 * K);   // A-frag: lane holds A[m=n][k=16c+4g+i]
            }
        }
        for (int b = 1; b <= 32; ++b){
            int t0 = 16*b;                 // computes u2[t0-16 .. t0)
            int guard = 1 << 20;
            while ((vwm[0] < (u32)t0) && --guard) __builtin_amdgcn_s_sleep(2);
            guard = 1 << 20;               // u2r space: need wave1 wm[2] >= t0-64
            while ((vwm[2] + 64u < (u32)t0) && --guard) __builtin_amdgcn_s_sleep(2);
            asm volatile("" ::: "memory");
            f16x4 B[4];
#pragma unroll
            for (int c = 0; c < 4; ++c)    // B[k][nn] = h1[t0-16+nn][k]
                B[c] = *(const f16x4*)&ring1[((t0-16+n) & 63)*ROW1 + 16*c + 4*g];
            f32x4 D[4];
#pragma unroll
            for (int r = 0; r < 4; ++r) D[r] = b2f[r];
#pragma unroll
            for (int c = 0; c < 4; ++c)
#pragma unroll
                for (int r = 0; r < 4; ++r)
                    D[r] = MFMA16(wi1[r][c], B[c], D[r]);
            int t = (t0 - 16 + n) & 63;    // D[m][nn]: lane holds rows 16r+4g+i, col nn=n
#pragma unroll
            for (int r = 0; r < 4; ++r)
                *(f32x4*)&u2r[t*U2P + 16*r + 4*g] = D[r];
            asm volatile("s_waitcnt lgkmcnt(0)" ::: "memory");
            vwm[1] = (u32)t0;
        }
    } else if (w == 1){
        // ---------------- wave1: h2 chain ----------------
        half2_t wr2[32];
        load_w16s(Whh1, lane, K, wr2);
        for (int c = 0; c < SEQn; ++c){
            if ((c & 15) == 0){
                asm volatile("s_waitcnt lgkmcnt(0)" ::: "memory");
                vwm[2] = (u32)c;
                int guard = 1 << 20;
                while ((vwm[1] < (u32)(c + 16)) && --guard) __builtin_amdgcn_s_sleep(2);
                guard = 1 << 20;           // ring2 space: need FC progress wm[3] >= c-48
                while ((vwm[3] + 48u < (u32)c) && --guard) __builtin_amdgcn_s_sleep(2);
                asm volatile("" ::: "memory");
            }
            float u2v = u2r[(c & 63)*U2P + lane];
            uint4 CUR[8];
            const uint4* hrow = (const uint4*)(ring2 + ((c-1) & 63)*ROW1);
#pragma unroll
            for (int j = 0; j < 8; ++j) CUR[j] = hrow[j];
            float y = dot64r8(CUR, wr2, u2v);
            ring2[(c & 63)*ROW1 + lane] = f2h(tanh_pre(y));
        }
        asm volatile("s_waitcnt lgkmcnt(0)" ::: "memory");
        vwm[2] = (u32)SEQn;
    } else {
        // ---------------- wave3: FC batches (MFMA) ----------------
        f16x4 wfcA[4]; f32x4 bfcf;
        {
            int mrow = (n < OUTn) ? n : (OUTn - 1);   // clamp pad rows (never stored)
#pragma unroll
            for (int c = 0; c < 4; ++c)
                wfcA[c] = cvt4(*(const f32x4*)&Wfc[mrow*HIDn + 16*c + 4*g]);  // unscaled
            int o0 = 4*g;
            bfcf.x = (o0+0 < OUTn) ? bfc[o0+0] : 0.f;
            bfcf.y = (o0+1 < OUTn) ? bfc[o0+1] : 0.f;
            bfcf.z = (o0+2 < OUTn) ? bfc[o0+2] : 0.f;
            bfcf.w = (o0+3 < OUTn) ? bfc[o0+3] : 0.f;
        }
        for (int b = 1; b <= 32; ++b){
            int f0 = 16*b;                 // FC[f0-16 .. f0)
            int guard = 1 << 20;
            while ((vwm[2] < (u32)f0) && --guard) __builtin_amdgcn_s_sleep(2);
            asm volatile("" ::: "memory");
            f16x4 B[4];
#pragma unroll
            for (int c = 0; c < 4; ++c)    // B[k][nn] = h2[f0-16+nn][k]
                B[c] = *(const f16x4*)&ring2[((f0-16+n) & 63)*ROW1 + 16*c + 4*g];
            f32x4 D = bfcf;
#pragma unroll
            for (int c = 0; c < 4; ++c)
                D = MFMA16(wfcA[c], B[c], D);
            int t = f0 - 16 + n;           // D[m][nn]: lane stores FC[t=f0-16+n][o=4g+i]
            float* o = out + t*OUTn + 4*g;
            if (g < 2){ o[0] = D.x; o[1] = D.y; o[2] = D.z; o[3] = D.w; }
            else if (g == 2){ o[0] = D.x; o[1] = D.y; }
            asm volatile("s_waitcnt lgkmcnt(0)" ::: "memory");
            vwm[3] = (u32)f0;
        }
    }
}

extern "C" void kernel_launch(void* const* d_in, const int* in_sizes, int n_in,
                              void* d_out, int out_size, void* d_ws, size_t ws_size,
                              hipStream_t stream){
    rnn_lastrow<<<dim3(1), dim3(256), 0, stream>>>(
        (const float*)d_in[0],
        (const float*)d_in[1], (const float*)d_in[2],
        (const float*)d_in[3], (const float*)d_in[4],
        (const float*)d_in[5], (const float*)d_in[6],
        (const float*)d_in[7], (const float*)d_in[8],
        (const float*)d_in[9], (const float*)d_in[10],
        (float*)d_out);
}